// Round 15
// baseline (125.570 us; speedup 1.0000x reference)
//
#include <hip/hip_runtime.h>
#include <math.h>

#define B_ 8
#define C_ 128
#define N_ 64
#define T_ 512
#define H_ 4
#define D_ 32
#define OUT_ 128
#define E_ 256
#define EP_ 320   // E + N self-loops
#define NEG_SLOPE 0.2f
#define BN_EPS 1e-5f

__device__ inline unsigned short f2bf(float f) {   // RNE float->bf16
  unsigned u = __float_as_uint(f);
  u += 0x7FFFu + ((u >> 16) & 1u);
  return (unsigned short)(u >> 16);
}
__device__ inline float bf2f(unsigned short s) {
  return __uint_as_float(((unsigned)s) << 16);
}

// ---- setup: wa[c][8] = W·att; in-CSR (src list grouped by dst) -----------------
__global__ void setup_kernel(const float* __restrict__ W,
                             const float* __restrict__ att_src,
                             const float* __restrict__ att_dst,
                             const int* __restrict__ edge_index,
                             float* __restrict__ wa,
                             int* __restrict__ iOff_g, int* __restrict__ iSrc_g) {
  __shared__ int icnt[N_], ibase[N_ + 1], ifill[N_];
  __shared__ int esrc[EP_], edst[EP_];
  int tid = threadIdx.x;

  for (int idx = tid; idx < C_ * 8; idx += blockDim.x) {
    int c = idx >> 3, j = idx & 7, h = j & 3;
    const float* att = (j < 4) ? att_src : att_dst;
    float s = 0.f;
    for (int d = 0; d < D_; ++d)
      s += W[(c * H_ + h) * D_ + d] * att[h * D_ + d];
    wa[idx] = s;
  }
  if (tid < N_) { icnt[tid] = 0; ifill[tid] = 0; }
  __syncthreads();
  for (int e = tid; e < EP_; e += blockDim.x) {
    int s, d;
    if (e < E_) { s = edge_index[e]; d = edge_index[E_ + e]; }
    else        { s = e - E_;        d = e - E_; }
    esrc[e] = s; edst[e] = d;
    atomicAdd(&icnt[d], 1);
  }
  __syncthreads();
  if (tid == 0) {
    int ai = 0;
    for (int n = 0; n < N_; ++n) { ibase[n] = ai; ai += icnt[n]; }
    ibase[N_] = ai;
  }
  __syncthreads();
  if (tid <= N_) iOff_g[tid] = ibase[tid];
  for (int e = tid; e < EP_; e += blockDim.x) {
    int d = edst[e];
    int pi = ibase[d] + atomicAdd(&ifill[d], 1);
    iSrc_g[pi] = esrc[e];
  }
}

// ---- K1: pure transpose x[b][c][n][t] (f32) -> xs[b][tc8][c][n][8t] (bf16) -----
// block = (b, c): reads ONE 128-KB c-plane fully sequentially (fill-pattern),
// LDS tile [64n][520t], writes 64 x 1-KB coalesced chunks. grid 1024 x 512 thr.
__global__ __launch_bounds__(512, 2)
void trans_kernel(const float* __restrict__ x,
                  unsigned short* __restrict__ xs) {
  __shared__ unsigned short tile[N_ * 520];   // 65 KB
  const int tid = threadIdx.x;
  const int b = blockIdx.x & 7;
  const int c = blockIdx.x >> 3;

  const float4* xp = reinterpret_cast<const float4*>(
      x + ((size_t)(b * C_ + c)) * (N_ * T_));
#pragma unroll
  for (int k = 0; k < 16; ++k) {
    int g = tid + k * 512;
    float4 v = xp[g];                 // sequential 1-KB wave runs
    int n = g >> 7;                   // 128 float4 per n-row
    int tcol = (g & 127) * 4;
    ushort4 s;
    s.x = f2bf(v.x); s.y = f2bf(v.y); s.z = f2bf(v.z); s.w = f2bf(v.w);
    *reinterpret_cast<ushort4*>(&tile[n * 520 + tcol]) = s;
  }
  __syncthreads();

  // store: 8 passes x (8 tc-chunks of 1 KB each); dst fully coalesced
  const int tcl = tid >> 6;           // 0..7
  const int n   = tid & 63;
#pragma unroll
  for (int p = 0; p < 8; ++p) {
    const int tc = p * 8 + tcl;
    uint4 v = *reinterpret_cast<const uint4*>(&tile[n * 520 + tc * 8]);
    unsigned short* dst = xs +
        ((((size_t)(b * 64 + tc) * C_ + c) * N_) + n) * 8;
    *reinterpret_cast<uint4*>(dst) = v;
  }
}

// ---- K2: fused a-GEMM + softmax + aggregation + epilogue -----------------------
// block = (b, tc8), grid 512 x 512 thr, 1 block/CU. Entire 128-KB bf16 tile
// staged once into LDS (XOR-swizzled); a computed in-block; w via LDS atomics.
__global__ __launch_bounds__(512, 1)
void fused_kernel(const unsigned short* __restrict__ xs,
                  const float* __restrict__ wa_g,
                  const float* __restrict__ Wm,
                  const int* __restrict__ iOff_g, const int* __restrict__ iSrc_g,
                  const float* __restrict__ bias,
                  const float* __restrict__ bn_gamma,
                  const float* __restrict__ bn_beta,
                  const float* __restrict__ bn_mean,
                  const float* __restrict__ bn_var,
                  float* __restrict__ out) {
  __shared__ unsigned short xt[C_ * 512];   // 128 KB, n XOR-swizzled per c
  __shared__ float a_l[8 * N_ * 8];         // [j][n][t] 16 KB; y overlay later
  __shared__ float w_l[N_ * 4 * 8];         // [n][h][t] 8 KB
  __shared__ float wal[C_ * 8];             // 4 KB
  __shared__ int iSrc[EP_];
  __shared__ int iOff[N_ + 1];

  const int tid = threadIdx.x;
  const int b  = blockIdx.x & 7;
  const int tc = blockIdx.x >> 3;
  const int t0 = tc * 8;

  for (int i = tid; i < C_ * 8; i += 512) wal[i] = wa_g[i];
  if (tid < EP_) iSrc[tid] = iSrc_g[tid];
  if (tid >= EP_ && tid < EP_ + N_ + 1) iOff[tid - EP_] = iOff_g[tid - EP_];
  for (int i = tid; i < N_ * 4 * 8; i += 512) w_l[i] = 0.f;

  // stage 128 KB contiguous, XOR-swizzle n by (c&7)
  {
    const uint4* src = reinterpret_cast<const uint4*>(
        xs + ((size_t)(b * 64 + tc) * C_) * 512);
#pragma unroll
    for (int k = 0; k < 16; ++k) {
      int g = tid + k * 512;
      uint4 v = src[g];
      int c = g >> 6;                 // 64 uint4 per 1024-B c-row
      int u = g & 63;
      int dstb = c * 1024 + ((u * 16) ^ ((c & 7) << 4));
      *reinterpret_cast<uint4*>(reinterpret_cast<char*>(xt) + dstb) = v;
    }
  }
  __syncthreads();

  const int n_  = tid >> 3;           // 0..63 (a/softmax role)
  const int t_  = tid & 7;

  // ---- a-GEMM: a[j][n][t] = sum_c xt[c][n][t] * wa[c][j] (registers) ----------
  {
    float av[8] = {0.f,0.f,0.f,0.f,0.f,0.f,0.f,0.f};
    for (int c = 0; c < C_; ++c) {
      float xv = bf2f(xt[c * 512 + ((n_ ^ (c & 7)) * 8 + t_)]);
      const float4 w0 = *reinterpret_cast<const float4*>(&wal[c * 8]);
      const float4 w1 = *reinterpret_cast<const float4*>(&wal[c * 8 + 4]);
      av[0] = fmaf(xv, w0.x, av[0]); av[1] = fmaf(xv, w0.y, av[1]);
      av[2] = fmaf(xv, w0.z, av[2]); av[3] = fmaf(xv, w0.w, av[3]);
      av[4] = fmaf(xv, w1.x, av[4]); av[5] = fmaf(xv, w1.y, av[5]);
      av[6] = fmaf(xv, w1.z, av[6]); av[7] = fmaf(xv, w1.w, av[7]);
    }
#pragma unroll
    for (int j = 0; j < 8; ++j) a_l[j * 512 + n_ * 8 + t_] = av[j];
  }
  __syncthreads();

  // ---- softmax B + scatter C': per (dst=n_, t=t_) -----------------------------
  {
    int e0 = iOff[n_], e1 = iOff[n_ + 1];
    float ad0 = a_l[4 * 512 + n_ * 8 + t_];
    float ad1 = a_l[5 * 512 + n_ * 8 + t_];
    float ad2 = a_l[6 * 512 + n_ * 8 + t_];
    float ad3 = a_l[7 * 512 + n_ * 8 + t_];
    float m0 = -1e30f, m1 = -1e30f, m2 = -1e30f, m3 = -1e30f;
    for (int e = e0; e < e1; ++e) {
      int s = iSrc[e];
      float v0 = a_l[0 * 512 + s * 8 + t_] + ad0; v0 = v0 > 0.f ? v0 : NEG_SLOPE * v0;
      float v1 = a_l[1 * 512 + s * 8 + t_] + ad1; v1 = v1 > 0.f ? v1 : NEG_SLOPE * v1;
      float v2 = a_l[2 * 512 + s * 8 + t_] + ad2; v2 = v2 > 0.f ? v2 : NEG_SLOPE * v2;
      float v3 = a_l[3 * 512 + s * 8 + t_] + ad3; v3 = v3 > 0.f ? v3 : NEG_SLOPE * v3;
      m0 = fmaxf(m0, v0); m1 = fmaxf(m1, v1);
      m2 = fmaxf(m2, v2); m3 = fmaxf(m3, v3);
    }
    float d0 = 0.f, d1 = 0.f, d2 = 0.f, d3 = 0.f;
    for (int e = e0; e < e1; ++e) {
      int s = iSrc[e];
      float v0 = a_l[0 * 512 + s * 8 + t_] + ad0; v0 = v0 > 0.f ? v0 : NEG_SLOPE * v0;
      float v1 = a_l[1 * 512 + s * 8 + t_] + ad1; v1 = v1 > 0.f ? v1 : NEG_SLOPE * v1;
      float v2 = a_l[2 * 512 + s * 8 + t_] + ad2; v2 = v2 > 0.f ? v2 : NEG_SLOPE * v2;
      float v3 = a_l[3 * 512 + s * 8 + t_] + ad3; v3 = v3 > 0.f ? v3 : NEG_SLOPE * v3;
      d0 += __expf(v0 - m0); d1 += __expf(v1 - m1);
      d2 += __expf(v2 - m2); d3 += __expf(v3 - m3);
    }
    float i0 = 1.f / (d0 * (float)N_);   // fold mean 1/N
    float i1 = 1.f / (d1 * (float)N_);
    float i2 = 1.f / (d2 * (float)N_);
    float i3 = 1.f / (d3 * (float)N_);
    for (int e = e0; e < e1; ++e) {
      int s = iSrc[e];
      float v0 = a_l[0 * 512 + s * 8 + t_] + ad0; v0 = v0 > 0.f ? v0 : NEG_SLOPE * v0;
      float v1 = a_l[1 * 512 + s * 8 + t_] + ad1; v1 = v1 > 0.f ? v1 : NEG_SLOPE * v1;
      float v2 = a_l[2 * 512 + s * 8 + t_] + ad2; v2 = v2 > 0.f ? v2 : NEG_SLOPE * v2;
      float v3 = a_l[3 * 512 + s * 8 + t_] + ad3; v3 = v3 > 0.f ? v3 : NEG_SLOPE * v3;
      atomicAdd(&w_l[(s * 4 + 0) * 8 + t_], __expf(v0 - m0) * i0);
      atomicAdd(&w_l[(s * 4 + 1) * 8 + t_], __expf(v1 - m1) * i1);
      atomicAdd(&w_l[(s * 4 + 2) * 8 + t_], __expf(v2 - m2) * i2);
      atomicAdd(&w_l[(s * 4 + 3) * 8 + t_], __expf(v3 - m3) * i3);
    }
  }
  __syncthreads();

  // ---- aggregation: y[h][c][t] = sum_n w[n][h][t] * xt[c][n][t] ---------------
  {
    const int c  = tid >> 2;          // 0..127
    const int tp = tid & 3;           // t = tp*2, tp*2+1
    float y0[4] = {0.f,0.f,0.f,0.f};
    float y1[4] = {0.f,0.f,0.f,0.f};
    for (int n = 0; n < N_; ++n) {
      ushort2 xv = *reinterpret_cast<const ushort2*>(
          &xt[c * 512 + ((n ^ (c & 7)) * 8 + tp * 2)]);
      float x0 = bf2f(xv.x), x1 = bf2f(xv.y);
#pragma unroll
      for (int h = 0; h < 4; ++h) {
        float2 wv = *reinterpret_cast<const float2*>(&w_l[(n * 4 + h) * 8 + tp * 2]);
        y0[h] = fmaf(x0, wv.x, y0[h]);
        y1[h] = fmaf(x1, wv.y, y1[h]);
      }
    }
    __syncthreads();                  // a_l dead -> overlay y_l [4h][128c][8t]
#pragma unroll
    for (int h = 0; h < 4; ++h) {
      a_l[(h * C_ + c) * 8 + tp * 2]     = y0[h];
      a_l[(h * C_ + c) * 8 + tp * 2 + 1] = y1[h];
    }
  }
  __syncthreads();

  // ---- epilogue: out[oc][t] = BN(sum_c y[h][c][t]*W[c][h][d] + bias) ----------
  {
    const int h  = tid >> 7;          // 0..3
    const int r  = (tid >> 3) & 15;   // d = r*2, r*2+1
    const int te = tid & 7;
    float o0 = 0.f, o1 = 0.f;
#pragma unroll 4
    for (int c = 0; c < C_; ++c) {
      float yv = a_l[(h * C_ + c) * 8 + te];
      const float2 wv = *reinterpret_cast<const float2*>(
          &Wm[((size_t)c * H_ + h) * D_ + r * 2]);
      o0 = fmaf(yv, wv.x, o0);
      o1 = fmaf(yv, wv.y, o1);
    }
    int oc = h * D_ + r * 2;
    float s0 = bn_gamma[oc] * rsqrtf(bn_var[oc] + BN_EPS);
    float s1 = bn_gamma[oc + 1] * rsqrtf(bn_var[oc + 1] + BN_EPS);
    out[((size_t)b * OUT_ + oc) * T_ + t0 + te] =
        (o0 + bias[oc]) * s0 + bn_beta[oc] - bn_mean[oc] * s0;
    out[((size_t)b * OUT_ + oc + 1) * T_ + t0 + te] =
        (o1 + bias[oc + 1]) * s1 + bn_beta[oc + 1] - bn_mean[oc + 1] * s1;
  }
}

extern "C" void kernel_launch(void* const* d_in, const int* in_sizes, int n_in,
                              void* d_out, int out_size, void* d_ws, size_t ws_size,
                              hipStream_t stream) {
  const float* x        = (const float*)d_in[0];
  const float* W        = (const float*)d_in[1];
  const float* att_src  = (const float*)d_in[2];
  const float* att_dst  = (const float*)d_in[3];
  const float* bias     = (const float*)d_in[4];
  const float* bn_gamma = (const float*)d_in[5];
  const float* bn_beta  = (const float*)d_in[6];
  const float* bn_mean  = (const float*)d_in[7];
  const float* bn_var   = (const float*)d_in[8];
  const int* edge_index = (const int*)d_in[9];
  float* out = (float*)d_out;

  char* ws = (char*)d_ws;
  float* wa   = (float*)ws;            // 4 KB
  int* iOff_g = (int*)(ws + 4096);     // 65 ints
  int* iSrc_g = (int*)(ws + 4608);     // 320 ints
  unsigned short* xs = (unsigned short*)(ws + 16384);   // 64 MB bf16 [b][tc8][c][n][8t]

  setup_kernel<<<1, 256, 0, stream>>>(W, att_src, att_dst, edge_index,
                                      wa, iOff_g, iSrc_g);
  trans_kernel<<<1024, 512, 0, stream>>>(x, xs);
  fused_kernel<<<512, 512, 0, stream>>>(xs, wa, W, iOff_g, iSrc_g,
                                        bias, bn_gamma, bn_beta, bn_mean, bn_var,
                                        out);
}

// Round 16
// 73.932 us; speedup vs baseline: 1.6984x; 1.6984x over previous
//
#include <hip/hip_runtime.h>
#include <math.h>

#define B_ 8
#define C_ 128
#define N_ 64
#define T_ 512
#define H_ 4
#define D_ 32
#define OUT_ 128
#define E_ 256
#define EP_ 320   // E + N self-loops
#define NEG_SLOPE 0.2f
#define BN_EPS 1e-5f
#define TC 16     // time steps per block
#define NT_ (N_ * T_)

// ---- setup: wa[c][8] = W·att; in-list (src per in-edge, grouped by dst);
// ----        out-list (dst per out-edge, grouped by src)
__global__ void setup_kernel(const float* __restrict__ W,
                             const float* __restrict__ att_src,
                             const float* __restrict__ att_dst,
                             const int* __restrict__ edge_index,
                             float* __restrict__ wa,
                             int* __restrict__ iOff_g, int* __restrict__ iSrc_g,
                             int* __restrict__ oOff_g, int* __restrict__ oDst_g) {
  __shared__ int icnt[N_], ibase[N_ + 1], ifill[N_];
  __shared__ int ocnt[N_], obase[N_ + 1], ofill[N_];
  __shared__ int esrc[EP_], edst[EP_];
  int tid = threadIdx.x;

  for (int idx = tid; idx < C_ * 8; idx += blockDim.x) {
    int c = idx >> 3, j = idx & 7, h = j & 3;
    const float* att = (j < 4) ? att_src : att_dst;
    float s = 0.f;
    for (int d = 0; d < D_; ++d)
      s += W[(c * H_ + h) * D_ + d] * att[h * D_ + d];
    wa[idx] = s;
  }
  if (tid < N_) { icnt[tid] = 0; ifill[tid] = 0; ocnt[tid] = 0; ofill[tid] = 0; }
  __syncthreads();
  for (int e = tid; e < EP_; e += blockDim.x) {
    int s, d;
    if (e < E_) { s = edge_index[e]; d = edge_index[E_ + e]; }
    else        { s = e - E_;        d = e - E_; }
    esrc[e] = s; edst[e] = d;
    atomicAdd(&icnt[d], 1);
    atomicAdd(&ocnt[s], 1);
  }
  __syncthreads();
  if (tid == 0) {
    int ai = 0, ao = 0;
    for (int n = 0; n < N_; ++n) {
      ibase[n] = ai; ai += icnt[n];
      obase[n] = ao; ao += ocnt[n];
    }
    ibase[N_] = ai; obase[N_] = ao;
  }
  __syncthreads();
  if (tid <= N_) { iOff_g[tid] = ibase[tid]; oOff_g[tid] = obase[tid]; }
  for (int e = tid; e < EP_; e += blockDim.x) {
    int s = esrc[e], d = edst[e];
    int pi = ibase[d] + atomicAdd(&ifill[d], 1);
    iSrc_g[pi] = s;
    int po = obase[s] + atomicAdd(&ofill[s], 1);
    oDst_g[po] = d;
  }
}

// ---- megakernel: one block per (b, 16-t chunk). grid = 256, block = 1024.
// 1 block/CU -> 16 waves/CU (4/SIMD). Phases:
// P1 proj (c split 4-way, LDS pairwise reduce) -> softmax B (z) -> C (w) ->
// P2 agg (float4 t-quad loads, n-half LDS reduce) -> P3 y·W + bias + BN.
__global__ __launch_bounds__(1024, 1)
void mega_kernel(const float* __restrict__ x,
                 const float* __restrict__ wa_g,
                 const float* __restrict__ Wm,
                 const int* __restrict__ iOff_g, const int* __restrict__ iSrc_g,
                 const int* __restrict__ oOff_g, const int* __restrict__ oDst_g,
                 const float* __restrict__ bias,
                 const float* __restrict__ bn_gamma,
                 const float* __restrict__ bn_beta,
                 const float* __restrict__ bn_mean,
                 const float* __restrict__ bn_var,
                 float* __restrict__ out) {
  __shared__ __align__(16) char arena[114688];
  float* a_l   = (float*)arena;                     // [8][64][20] 40960B; y overlay [4][128][17]
  float4* redA = (float4*)(arena + 40960);          // 32KB (pass1 scratch)
  float4* redB = (float4*)(arena + 73728);          // 32KB (pass1 scratch / pass2 scr)
  float* z_l   = (float*)(arena + 40960);           // [64][16][4] 16KB (post-P1)
  float* w_l   = (float*)(arena + 57344);           // [n*64+h*16+t] 16KB (post-P1)
  float* scr2  = (float*)(arena + 73728);           // 32KB pass2 n-half reduce
  float* wstage= (float*)(arena + 40960);           // 64KB W stage (P3)
  float* wal   = (float*)(arena + 106496);          // 4KB
  int* iSrc = (int*)(arena + 110592);
  int* oDst = iSrc + EP_;
  int* iOff = oDst + EP_;
  int* oOff = iOff + (N_ + 1);

  const int tid = threadIdx.x;
  const int b = blockIdx.x & 7;              // batch -> XCD pinning
  const int tchunk = blockIdx.x >> 3;        // 0..31
  const int t0 = tchunk * TC;

  if (tid < EP_) { iSrc[tid] = iSrc_g[tid]; oDst[tid] = oDst_g[tid]; }
  if (tid >= EP_ && tid < EP_ + N_ + 1) {
    int i = tid - EP_;
    iOff[i] = iOff_g[i]; oOff[i] = oOff_g[i];
  }
  if (tid < C_ * 8) wal[tid] = wa_g[tid];
  __syncthreads();

  // ---------------- pass 1: a[j][n][t] = sum_c x[b][c][n][t]*wa[c][j] ----------
  {
    const int q  = tid & 3;          // t-quad
    const int cq = (tid >> 2) & 3;   // c quarter
    const int n1 = tid >> 4;         // node 0..63
    const float* xp = x + ((size_t)(b * C_ + cq * 32) * N_ + n1) * T_ + t0 + q * 4;
    float4 acc[8];
#pragma unroll
    for (int j = 0; j < 8; ++j) { acc[j].x = 0.f; acc[j].y = 0.f; acc[j].z = 0.f; acc[j].w = 0.f; }
    for (int kb = 0; kb < 4; ++kb) {
      float4 xv[8];
#pragma unroll
      for (int u = 0; u < 8; ++u)
        xv[u] = *reinterpret_cast<const float4*>(xp + (size_t)(kb * 8 + u) * NT_);
#pragma unroll
      for (int u = 0; u < 8; ++u) {
        const int c = cq * 32 + kb * 8 + u;
        const float4 w0 = *reinterpret_cast<const float4*>(&wal[c * 8]);
        const float4 w1 = *reinterpret_cast<const float4*>(&wal[c * 8 + 4]);
        const float4 xu = xv[u];
        acc[0].x = fmaf(xu.x, w0.x, acc[0].x); acc[0].y = fmaf(xu.y, w0.x, acc[0].y);
        acc[0].z = fmaf(xu.z, w0.x, acc[0].z); acc[0].w = fmaf(xu.w, w0.x, acc[0].w);
        acc[1].x = fmaf(xu.x, w0.y, acc[1].x); acc[1].y = fmaf(xu.y, w0.y, acc[1].y);
        acc[1].z = fmaf(xu.z, w0.y, acc[1].z); acc[1].w = fmaf(xu.w, w0.y, acc[1].w);
        acc[2].x = fmaf(xu.x, w0.z, acc[2].x); acc[2].y = fmaf(xu.y, w0.z, acc[2].y);
        acc[2].z = fmaf(xu.z, w0.z, acc[2].z); acc[2].w = fmaf(xu.w, w0.z, acc[2].w);
        acc[3].x = fmaf(xu.x, w0.w, acc[3].x); acc[3].y = fmaf(xu.y, w0.w, acc[3].y);
        acc[3].z = fmaf(xu.z, w0.w, acc[3].z); acc[3].w = fmaf(xu.w, w0.w, acc[3].w);
        acc[4].x = fmaf(xu.x, w1.x, acc[4].x); acc[4].y = fmaf(xu.y, w1.x, acc[4].y);
        acc[4].z = fmaf(xu.z, w1.x, acc[4].z); acc[4].w = fmaf(xu.w, w1.x, acc[4].w);
        acc[5].x = fmaf(xu.x, w1.y, acc[5].x); acc[5].y = fmaf(xu.y, w1.y, acc[5].y);
        acc[5].z = fmaf(xu.z, w1.y, acc[5].z); acc[5].w = fmaf(xu.w, w1.y, acc[5].w);
        acc[6].x = fmaf(xu.x, w1.z, acc[6].x); acc[6].y = fmaf(xu.y, w1.z, acc[6].y);
        acc[6].z = fmaf(xu.z, w1.z, acc[6].z); acc[6].w = fmaf(xu.w, w1.z, acc[6].w);
        acc[7].x = fmaf(xu.x, w1.w, acc[7].x); acc[7].y = fmaf(xu.y, w1.w, acc[7].y);
        acc[7].z = fmaf(xu.z, w1.w, acc[7].z); acc[7].w = fmaf(xu.w, w1.w, acc[7].w);
      }
    }
    // 2-stage pairwise reduce: cq1 -> redA, cq3 -> redB
    if (cq == 1) {
#pragma unroll
      for (int j = 0; j < 8; ++j) redA[(j * 64 + n1) * 4 + q] = acc[j];
    } else if (cq == 3) {
#pragma unroll
      for (int j = 0; j < 8; ++j) redB[(j * 64 + n1) * 4 + q] = acc[j];
    }
    __syncthreads();
    if (cq == 0) {
#pragma unroll
      for (int j = 0; j < 8; ++j) {
        float4 o = redA[(j * 64 + n1) * 4 + q];
        acc[j].x += o.x; acc[j].y += o.y; acc[j].z += o.z; acc[j].w += o.w;
      }
    } else if (cq == 2) {
#pragma unroll
      for (int j = 0; j < 8; ++j) {
        float4 o = redB[(j * 64 + n1) * 4 + q];
        acc[j].x += o.x; acc[j].y += o.y; acc[j].z += o.z; acc[j].w += o.w;
        redB[(j * 64 + n1) * 4 + q] = acc[j];
      }
    }
    __syncthreads();
    if (cq == 0) {
#pragma unroll
      for (int j = 0; j < 8; ++j) {
        float4 o = redB[(j * 64 + n1) * 4 + q];
        float4 r;
        r.x = acc[j].x + o.x; r.y = acc[j].y + o.y;
        r.z = acc[j].z + o.z; r.w = acc[j].w + o.w;
        *reinterpret_cast<float4*>(&a_l[j * 1280 + n1 * 20 + q * 4]) = r;
      }
    }
    __syncthreads();
  }

  // ---------------- softmax B: per (dst,t): z = exp(-m)/(den*N) ----------------
  {
    const int t = tid & 15, nd = tid >> 4;   // exactly 64x16 = 1024 items
    int e0 = iOff[nd], e1 = iOff[nd + 1];
    float ad0 = a_l[4 * 1280 + nd * 20 + t];
    float ad1 = a_l[5 * 1280 + nd * 20 + t];
    float ad2 = a_l[6 * 1280 + nd * 20 + t];
    float ad3 = a_l[7 * 1280 + nd * 20 + t];
    float m0 = -1e30f, m1 = -1e30f, m2 = -1e30f, m3 = -1e30f;
    for (int e = e0; e < e1; ++e) {
      int s = iSrc[e];
      float v0 = a_l[0 * 1280 + s * 20 + t] + ad0; v0 = v0 > 0.f ? v0 : NEG_SLOPE * v0;
      float v1 = a_l[1 * 1280 + s * 20 + t] + ad1; v1 = v1 > 0.f ? v1 : NEG_SLOPE * v1;
      float v2 = a_l[2 * 1280 + s * 20 + t] + ad2; v2 = v2 > 0.f ? v2 : NEG_SLOPE * v2;
      float v3 = a_l[3 * 1280 + s * 20 + t] + ad3; v3 = v3 > 0.f ? v3 : NEG_SLOPE * v3;
      m0 = fmaxf(m0, v0); m1 = fmaxf(m1, v1);
      m2 = fmaxf(m2, v2); m3 = fmaxf(m3, v3);
    }
    float d0 = 0.f, d1 = 0.f, d2 = 0.f, d3 = 0.f;
    for (int e = e0; e < e1; ++e) {
      int s = iSrc[e];
      float v0 = a_l[0 * 1280 + s * 20 + t] + ad0; v0 = v0 > 0.f ? v0 : NEG_SLOPE * v0;
      float v1 = a_l[1 * 1280 + s * 20 + t] + ad1; v1 = v1 > 0.f ? v1 : NEG_SLOPE * v1;
      float v2 = a_l[2 * 1280 + s * 20 + t] + ad2; v2 = v2 > 0.f ? v2 : NEG_SLOPE * v2;
      float v3 = a_l[3 * 1280 + s * 20 + t] + ad3; v3 = v3 > 0.f ? v3 : NEG_SLOPE * v3;
      d0 += __expf(v0 - m0); d1 += __expf(v1 - m1);
      d2 += __expf(v2 - m2); d3 += __expf(v3 - m3);
    }
    float4 zv;
    zv.x = __expf(-m0) / (d0 * (float)N_);
    zv.y = __expf(-m1) / (d1 * (float)N_);
    zv.z = __expf(-m2) / (d2 * (float)N_);
    zv.w = __expf(-m3) / (d3 * (float)N_);
    __syncthreads();   // a_l stable; z region (redA alias) free after P1
    *reinterpret_cast<float4*>(&z_l[(nd * 16 + t) * 4]) = zv;
  }
  __syncthreads();

  // ---------------- softmax C: per (src,t) gather -> w[n][h][t] ----------------
  {
    const int t = tid & 15, src = tid >> 4;
    int e0 = oOff[src], e1 = oOff[src + 1];
    float as0 = a_l[0 * 1280 + src * 20 + t];
    float as1 = a_l[1 * 1280 + src * 20 + t];
    float as2 = a_l[2 * 1280 + src * 20 + t];
    float as3 = a_l[3 * 1280 + src * 20 + t];
    float w0 = 0.f, w1 = 0.f, w2 = 0.f, w3 = 0.f;
    for (int e = e0; e < e1; ++e) {
      int d = oDst[e];
      float4 zv = *reinterpret_cast<const float4*>(&z_l[(d * 16 + t) * 4]);
      float v0 = as0 + a_l[4 * 1280 + d * 20 + t]; v0 = v0 > 0.f ? v0 : NEG_SLOPE * v0;
      float v1 = as1 + a_l[5 * 1280 + d * 20 + t]; v1 = v1 > 0.f ? v1 : NEG_SLOPE * v1;
      float v2 = as2 + a_l[6 * 1280 + d * 20 + t]; v2 = v2 > 0.f ? v2 : NEG_SLOPE * v2;
      float v3 = as3 + a_l[7 * 1280 + d * 20 + t]; v3 = v3 > 0.f ? v3 : NEG_SLOPE * v3;
      w0 += __expf(v0) * zv.x;
      w1 += __expf(v1) * zv.y;
      w2 += __expf(v2) * zv.z;
      w3 += __expf(v3) * zv.w;
    }
    w_l[src * 64 +  0 + t] = w0;
    w_l[src * 64 + 16 + t] = w1;
    w_l[src * 64 + 32 + t] = w2;
    w_l[src * 64 + 48 + t] = w3;
  }
  __syncthreads();

  // ---------------- pass 2: y[h][c][t] = sum_n w[n][h][t] * x[b][c][n][t] ------
  // thread = (c 0..127, n-half, t-quad); float4 loads on t (4x fewer VMEM instrs)
  {
    const int c  = tid >> 3;
    const int ns = (tid >> 2) & 1;
    const int tq = tid & 3;
    const float* xp = x + ((size_t)(b * C_ + c) * N_ + ns * 32) * T_ + t0 + tq * 4;
    float4 yr[4];
#pragma unroll
    for (int h = 0; h < 4; ++h) { yr[h].x = 0.f; yr[h].y = 0.f; yr[h].z = 0.f; yr[h].w = 0.f; }
    for (int nb = 0; nb < 4; ++nb) {
      float4 xv[8];
#pragma unroll
      for (int u = 0; u < 8; ++u)
        xv[u] = *reinterpret_cast<const float4*>(xp + (size_t)(nb * 8 + u) * T_);
#pragma unroll
      for (int u = 0; u < 8; ++u) {
        const int n = ns * 32 + nb * 8 + u;
#pragma unroll
        for (int h = 0; h < 4; ++h) {
          float4 wv = *reinterpret_cast<const float4*>(&w_l[n * 64 + h * 16 + tq * 4]);
          yr[h].x = fmaf(xv[u].x, wv.x, yr[h].x);
          yr[h].y = fmaf(xv[u].y, wv.y, yr[h].y);
          yr[h].z = fmaf(xv[u].z, wv.z, yr[h].z);
          yr[h].w = fmaf(xv[u].w, wv.w, yr[h].w);
        }
      }
    }
    if (ns == 1) {
#pragma unroll
      for (int h = 0; h < 4; ++h)
        *reinterpret_cast<float4*>(&scr2[((h * 128 + c) * 4 + tq) * 4]) = yr[h];
    }
    __syncthreads();
    if (ns == 0) {
      float* y_l = a_l;                      // overlay (a dead after C)
#pragma unroll
      for (int h = 0; h < 4; ++h) {
        float4 o = *reinterpret_cast<const float4*>(&scr2[((h * 128 + c) * 4 + tq) * 4]);
        y_l[h * 2176 + c * 17 + tq * 4 + 0] = yr[h].x + o.x;
        y_l[h * 2176 + c * 17 + tq * 4 + 1] = yr[h].y + o.y;
        y_l[h * 2176 + c * 17 + tq * 4 + 2] = yr[h].z + o.z;
        y_l[h * 2176 + c * 17 + tq * 4 + 3] = yr[h].w + o.w;
      }
    }
  }
  __syncthreads();

  // ---------------- pass 3: stage W; out = BN(y·W + bias) ----------------------
  {
    const float4* Wm4 = reinterpret_cast<const float4*>(Wm);
    float4* ws4 = reinterpret_cast<float4*>(wstage);
#pragma unroll
    for (int r = 0; r < 4; ++r) ws4[r * 1024 + tid] = Wm4[r * 1024 + tid];
  }
  __syncthreads();
  {
    const int t3 = tid & 15;
    const int g = tid >> 4;        // 0..63
    const int h = g >> 4;          // 0..3
    const int dp = g & 15;         // d = dp*2, dp*2+1
    const float* y_l = a_l;
    float acc0 = 0.f, acc1 = 0.f;
#pragma unroll 8
    for (int c = 0; c < C_; ++c) {
      float yv = y_l[h * 2176 + c * 17 + t3];
      const float2 wv = *reinterpret_cast<const float2*>(
          &wstage[(c * H_ + h) * D_ + dp * 2]);
      acc0 = fmaf(yv, wv.x, acc0);
      acc1 = fmaf(yv, wv.y, acc1);
    }
    int oc = h * D_ + dp * 2;
    float s0 = bn_gamma[oc] * rsqrtf(bn_var[oc] + BN_EPS);
    float s1 = bn_gamma[oc + 1] * rsqrtf(bn_var[oc + 1] + BN_EPS);
    out[((size_t)b * OUT_ + oc) * T_ + t0 + t3] =
        (acc0 + bias[oc]) * s0 + bn_beta[oc] - bn_mean[oc] * s0;
    out[((size_t)b * OUT_ + oc + 1) * T_ + t0 + t3] =
        (acc1 + bias[oc + 1]) * s1 + bn_beta[oc + 1] - bn_mean[oc + 1] * s1;
  }
}

extern "C" void kernel_launch(void* const* d_in, const int* in_sizes, int n_in,
                              void* d_out, int out_size, void* d_ws, size_t ws_size,
                              hipStream_t stream) {
  const float* x        = (const float*)d_in[0];
  const float* W        = (const float*)d_in[1];
  const float* att_src  = (const float*)d_in[2];
  const float* att_dst  = (const float*)d_in[3];
  const float* bias     = (const float*)d_in[4];
  const float* bn_gamma = (const float*)d_in[5];
  const float* bn_beta  = (const float*)d_in[6];
  const float* bn_mean  = (const float*)d_in[7];
  const float* bn_var   = (const float*)d_in[8];
  const int* edge_index = (const int*)d_in[9];
  float* out = (float*)d_out;

  char* ws = (char*)d_ws;
  float* wa   = (float*)ws;            // 4 KB
  int* iOff_g = (int*)(ws + 4096);     // 65 ints
  int* iSrc_g = (int*)(ws + 4608);     // 320 ints
  int* oOff_g = (int*)(ws + 6144);     // 65 ints
  int* oDst_g = (int*)(ws + 6656);     // 320 ints

  setup_kernel<<<1, 256, 0, stream>>>(W, att_src, att_dst, edge_index, wa,
                                      iOff_g, iSrc_g, oOff_g, oDst_g);
  mega_kernel<<<256, 1024, 0, stream>>>(x, wa, W, iOff_g, iSrc_g, oOff_g, oDst_g,
                                        bias, bn_gamma, bn_beta, bn_mean, bn_var,
                                        out);
}